// Round 5
// baseline (687.767 us; speedup 1.0000x reference)
//
#include <hip/hip_runtime.h>

// v: [E, 64, 3] f32, k: [E, 8, 16] f32, q: [N, 8, 16] f32, dst: [E] i32
// out: [N, 64, 3] f32.  H=8 heads, T=16, 8 value channels/head, D=3.
//
// Fully-streamed design: the dst permutation is applied on the OUTPUT side
// (38.4 MB, L2/L3-resident atomics) so all DRAM traffic (k, v) is sequential.
#define HH 8
#define BSTRIDE 256  // bucket capacity = max supported degree (Poisson(16))

static constexpr float SCALE = 0.08838834764831843f;  // 1/sqrt(8*16)

typedef float vf4 __attribute__((ext_vector_type(4)));

// Pass 1 (edge-major): stream k nontemporal, gather q (L3-resident, 16x
// reuse), logits -> lgE[e*8+h] coalesced; bucket-append edge id (1 atomic).
__global__ __launch_bounds__(256) void edge_logits_kernel(
    const float* __restrict__ k, const float* __restrict__ q,
    const int* __restrict__ dst, int* __restrict__ cursor,
    int* __restrict__ eid, float* __restrict__ lgE, int E) {
  int t = blockIdx.x * 256 + threadIdx.x;
  int e = t >> 3;
  if (e >= E) return;
  int h = t & 7;
  int d = dst[e];  // 8 lanes per edge -> broadcast load

  const vf4* kk = (const vf4*)(k + (size_t)e * 128 + h * 16);
  const vf4* qq = (const vf4*)(q + (size_t)d * 128 + h * 16);
  vf4 a0 = __builtin_nontemporal_load(kk + 0);
  vf4 a1 = __builtin_nontemporal_load(kk + 1);
  vf4 a2 = __builtin_nontemporal_load(kk + 2);
  vf4 a3 = __builtin_nontemporal_load(kk + 3);
  vf4 b0 = qq[0], b1 = qq[1], b2 = qq[2], b3 = qq[3];
  float acc = a0.x * b0.x + a0.y * b0.y + a0.z * b0.z + a0.w * b0.w;
  acc += a1.x * b1.x + a1.y * b1.y + a1.z * b1.z + a1.w * b1.w;
  acc += a2.x * b2.x + a2.y * b2.y + a2.z * b2.z + a2.w * b2.w;
  acc += a3.x * b3.x + a3.y * b3.y + a3.z * b3.z + a3.w * b3.w;
  lgE[t] = acc * SCALE;  // edge-major, coalesced, stays in L3

  if (h == 0) {
    int pos = atomicAdd(&cursor[d], 1);
    if (pos < BSTRIDE) eid[d * BSTRIDE + pos] = e;
  }
}

// Pass 2 (node-major): one wave per node. Gather this node's logits via the
// bucket (L3-hot), reduce per-head max and denom with shuffles, then
// overwrite lgE in place with normalized weights a[e,h]. Wave-private LDS,
// no __syncthreads. Each lgE slot belongs to exactly one node: no races.
__global__ __launch_bounds__(256) void softmax_kernel(
    float* __restrict__ lgE, const int* __restrict__ cursor,
    const int* __restrict__ eid, int N) {
  __shared__ int eidL[4][BSTRIDE];
  int wave = threadIdx.x >> 6;
  int lane = threadIdx.x & 63;
  int node = blockIdx.x * 4 + wave;
  if (node >= N) return;

  int deg = min(cursor[node], BSTRIDE);
  const int* bucket = eid + node * BSTRIDE;
  for (int i = lane; i < deg; i += 64) eidL[wave][i] = bucket[i];
  // lockstep wave: eidL writes precede reads in program order, no barrier

  int n8 = deg * 8;  // lane i covers (slot i>>3, head i&7); 64%8==0 so the
                     // head owned by a lane is invariant: h = lane&7.

  // per-head max
  float m = -1e30f;
  for (int i = lane; i < n8; i += 64) {
    int e = eidL[wave][i >> 3];
    m = fmaxf(m, lgE[e * 8 + (i & 7)]);
  }
  m = fmaxf(m, __shfl_xor(m, 8, 64));
  m = fmaxf(m, __shfl_xor(m, 16, 64));
  m = fmaxf(m, __shfl_xor(m, 32, 64));

  // per-head denom (re-read lgE: L2/L3-hot)
  float s = 0.f;
  for (int i = lane; i < n8; i += 64) {
    int e = eidL[wave][i >> 3];
    s += __expf(lgE[e * 8 + (i & 7)] - m);
  }
  s += __shfl_xor(s, 8, 64);
  s += __shfl_xor(s, 16, 64);
  s += __shfl_xor(s, 32, 64);
  float inv = (s > 0.f) ? 1.0f / s : 0.f;

  // overwrite logits with weights
  for (int i = lane; i < n8; i += 64) {
    int e = eidL[wave][i >> 3];
    float lg = lgE[e * 8 + (i & 7)];
    lgE[e * 8 + (i & 7)] = __expf(lg - m) * inv;
  }
}

// Pass 3 (edge-major): one wave per edge. Stream v nontemporal (768B/wave,
// sequential across waves), stream weights, atomic-scatter into out
// (38.4 MB, L2/L3-resident RMW). Channel layout idx = i*64+lane keeps each
// vector atomic on 4 consecutive lines (12 line-RMWs per edge total).
__global__ __launch_bounds__(256) void scatter_kernel(
    const float* __restrict__ v, const float* __restrict__ lgE,
    const int* __restrict__ dst, float* __restrict__ out, int E) {
  int w = blockIdx.x * 4 + (threadIdx.x >> 6);
  if (w >= E) return;
  int lane = threadIdx.x & 63;
  int e = w;
  int d = dst[e];  // broadcast within wave

  const float* vr = v + (size_t)e * 192;
  const float* wr = lgE + (size_t)e * 8;
  float* orow = out + (size_t)d * 192;
#pragma unroll
  for (int i = 0; i < 3; ++i) {
    int idx = i * 64 + lane;       // flat dword in the 192-float row
    float wt = wr[idx / 24];       // head = idx / (8 ch * 3 comp)
    float val = __builtin_nontemporal_load(vr + idx);
    atomicAdd(orow + idx, wt * val);
  }
}

extern "C" void kernel_launch(void* const* d_in, const int* in_sizes, int n_in,
                              void* d_out, int out_size, void* d_ws,
                              size_t ws_size, hipStream_t stream) {
  const float* v = (const float*)d_in[0];
  const float* k = (const float*)d_in[1];
  const float* q = (const float*)d_in[2];
  const int* dst = (const int*)d_in[3];
  float* out = (float*)d_out;

  const int E = in_sizes[3];              // 800000
  const int N = in_sizes[2] / (HH * 16);  // 50000

  // Workspace: cursor[N] | eid[N*256] | lgE[E*8]
  char* ws = (char*)d_ws;
  size_t off = 0;
  auto take = [&](size_t bytes) {
    void* p = ws + off;
    off += (bytes + 255) & ~(size_t)255;
    return p;
  };
  int* cursor = (int*)take((size_t)N * sizeof(int));
  int* eid = (int*)take((size_t)N * BSTRIDE * sizeof(int));
  float* lgE = (float*)take((size_t)E * HH * sizeof(float));

  hipMemsetAsync(cursor, 0, (size_t)N * sizeof(int), stream);
  hipMemsetAsync(out, 0, (size_t)out_size * sizeof(float), stream);

  edge_logits_kernel<<<(E * 8 + 255) / 256, 256, 0, stream>>>(k, q, dst, cursor,
                                                              eid, lgE, E);
  softmax_kernel<<<(N + 3) / 4, 256, 0, stream>>>(lgE, cursor, eid, N);
  scatter_kernel<<<(E + 3) / 4, 256, 0, stream>>>(v, lgE, dst, out, E);
}

// Round 6
// 304.006 us; speedup vs baseline: 2.2623x; 2.2623x over previous
//
#include <hip/hip_runtime.h>

// v: [E, 64, 3] f32, k: [E, 8, 16] f32, q: [N, 8, 16] f32, dst: [E] i32
// out: [N, 64, 3] f32.  H=8 heads, T=16, 8 value channels/head, D=3.
//
// Structure: (A) edge-major pass streams k at full BW (the only way k avoids
// a random 410MB gather), gathers q (25.6MB, L3-resident, 16x reuse), writes
// logits edge-major (coalesced, 25.6MB -> stays in L2/L3 for pass C), and
// bucket-appends edge ids. (C) node-major pass: gather logits (cache-hot),
// LDS softmax, gather v (614MB random 768B -- the one compulsory gather),
// write out. The dst permutation is applied ONLY to cache-resident data.
#define HH 8
#define CAPL 128     // per-wave LDS cache (Poisson(16): P(deg>128) ~ 1e-58)
#define BSTRIDE 256  // bucket capacity = max supported degree

static constexpr float SCALE = 0.08838834764831843f;  // 1/sqrt(8*16)

struct f3 {
  float x, y, z;
};  // stride-12 loads -> global_load_dwordx3

typedef float vf4 __attribute__((ext_vector_type(4)));

// Pass A: 8 lanes per edge. Stream k nontemporal; gather q; lgE[e*8+h]
// coalesced write; one bucket atomic per edge.
__global__ __launch_bounds__(256) void edge_logits_kernel(
    const float* __restrict__ k, const float* __restrict__ q,
    const int* __restrict__ dst, int* __restrict__ cursor,
    int* __restrict__ eid, float* __restrict__ lgE, int E) {
  int t = blockIdx.x * 256 + threadIdx.x;
  int e = t >> 3;
  if (e >= E) return;
  int h = t & 7;
  int d = dst[e];  // 8-lane broadcast

  const vf4* kk = (const vf4*)(k + (size_t)e * 128 + h * 16);
  const vf4* qq = (const vf4*)(q + (size_t)d * 128 + h * 16);
  vf4 a0 = __builtin_nontemporal_load(kk + 0);
  vf4 a1 = __builtin_nontemporal_load(kk + 1);
  vf4 a2 = __builtin_nontemporal_load(kk + 2);
  vf4 a3 = __builtin_nontemporal_load(kk + 3);
  vf4 b0 = qq[0], b1 = qq[1], b2 = qq[2], b3 = qq[3];
  float acc = a0.x * b0.x + a0.y * b0.y + a0.z * b0.z + a0.w * b0.w;
  acc += a1.x * b1.x + a1.y * b1.y + a1.z * b1.z + a1.w * b1.w;
  acc += a2.x * b2.x + a2.y * b2.y + a2.z * b2.z + a2.w * b2.w;
  acc += a3.x * b3.x + a3.y * b3.y + a3.z * b3.z + a3.w * b3.w;
  lgE[t] = acc * SCALE;  // edge-major, coalesced, L2/L3-resident for pass C

  if (h == 0) {
    int pos = atomicAdd(&cursor[d], 1);
    if (pos < BSTRIDE) eid[d * BSTRIDE + pos] = e;
  }
}

// Pass C: one wave per node. Bucket eids -> LDS; gather lgE (32B/edge,
// cache-hot); softmax in LDS; gather v (768B/edge, DRAM); write out.
// All LDS wave-private, no __syncthreads.
__global__ __launch_bounds__(256) void node_kernel(
    const float* __restrict__ v, const float* __restrict__ lgE,
    const int* __restrict__ cursor, const int* __restrict__ eid,
    float* __restrict__ out, int N) {
  __shared__ int eidL[4][CAPL];
  __shared__ float wL[4][CAPL * HH];

  int tid = threadIdx.x;
  int wave = tid >> 6;
  int lane = tid & 63;
  int node = blockIdx.x * 4 + wave;
  if (node >= N) return;

  int deg = min(cursor[node], BSTRIDE);
  int nl = min(deg, CAPL);
  const int* bucket = eid + node * BSTRIDE;
  const char* vB = (const char*)v;
  uint32_t vlane = (uint32_t)(lane * 12);

  for (int i = lane; i < nl; i += 64) eidL[wave][i] = bucket[i];
  // lockstep wave: LDS writes precede reads in program order, no barrier

  // Phase 1: gather raw logits -> LDS + per-head max. Lane i covers
  // (slot i>>3, head i&7); 64%8==0 so each lane's head is fixed: h=lane&7.
  float m = -1e30f;
  for (int i = lane; i < nl * 8; i += 64) {
    int e = eidL[wave][i >> 3];
    float lg = lgE[e * 8 + (i & 7)];  // 8 lanes/edge: 32B chunk, cache-hot
    wL[wave][i] = lg;
    m = fmaxf(m, lg);
  }
  for (int i = CAPL * 8 + lane; i < deg * 8; i += 64) {  // overflow (never)
    int e = bucket[i >> 3];
    m = fmaxf(m, lgE[e * 8 + (i & 7)]);
  }
  m = fmaxf(m, __shfl_xor(m, 8, 64));
  m = fmaxf(m, __shfl_xor(m, 16, 64));
  m = fmaxf(m, __shfl_xor(m, 32, 64));

  // Phase 2: exp in place + denom.
  float s = 0.f;
  for (int i = lane; i < nl * 8; i += 64) {
    float ex = __expf(wL[wave][i] - m);
    wL[wave][i] = ex;
    s += ex;
  }
  for (int i = CAPL * 8 + lane; i < deg * 8; i += 64) {  // overflow (never)
    int e = bucket[i >> 3];
    s += __expf(lgE[e * 8 + (i & 7)] - m);
  }
  s += __shfl_xor(s, 8, 64);
  s += __shfl_xor(s, 16, 64);
  s += __shfl_xor(s, 32, 64);
  float inv = (s > 0.f) ? 1.0f / s : 0.f;  // deg==0 -> zeros, not NaN

  // Phase 3: channel accumulation. Lane owns channel `lane`, head hc=lane>>3.
  // Unroll x4: 4 independent dwordx3 v-loads in flight.
  int hc = lane >> 3;
  float minv = __shfl(inv, hc, 64);
  float m_c = __shfl(m, hc, 64);
  float a0 = 0.f, a1 = 0.f, a2 = 0.f;
  int i = 0;
  for (; i + 4 <= nl; i += 4) {
    int e0 = eidL[wave][i + 0];
    int e1 = eidL[wave][i + 1];
    int e2 = eidL[wave][i + 2];
    int e3 = eidL[wave][i + 3];
    float w0 = wL[wave][(i + 0) * 8 + hc];
    float w1 = wL[wave][(i + 1) * 8 + hc];
    float w2 = wL[wave][(i + 2) * 8 + hc];
    float w3 = wL[wave][(i + 3) * 8 + hc];
    f3 v0 = *(const f3*)(vB + (uint32_t)e0 * 768u + vlane);
    f3 v1 = *(const f3*)(vB + (uint32_t)e1 * 768u + vlane);
    f3 v2 = *(const f3*)(vB + (uint32_t)e2 * 768u + vlane);
    f3 v3 = *(const f3*)(vB + (uint32_t)e3 * 768u + vlane);
    a0 += w0 * v0.x + w1 * v1.x + w2 * v2.x + w3 * v3.x;
    a1 += w0 * v0.y + w1 * v1.y + w2 * v2.y + w3 * v3.y;
    a2 += w0 * v0.z + w1 * v1.z + w2 * v2.z + w3 * v3.z;
  }
  for (; i < nl; ++i) {
    int e = eidL[wave][i];
    float w = wL[wave][i * 8 + hc];
    f3 vv = *(const f3*)(vB + (uint32_t)e * 768u + vlane);
    a0 += w * vv.x;
    a1 += w * vv.y;
    a2 += w * vv.z;
  }
  for (; i < deg; ++i) {  // overflow (never in practice)
    int e = bucket[i];
    float w = __expf(lgE[e * 8 + hc] - m_c);  // un-normalized, minv at end
    f3 vv = *(const f3*)(vB + (uint32_t)e * 768u + vlane);
    a0 += w * vv.x;
    a1 += w * vv.y;
    a2 += w * vv.z;
  }
  a0 *= minv;
  a1 *= minv;
  a2 *= minv;

  f3* op = (f3*)((char*)out + (uint32_t)node * 768u + vlane);
  op->x = a0;
  op->y = a1;
  op->z = a2;
}

extern "C" void kernel_launch(void* const* d_in, const int* in_sizes, int n_in,
                              void* d_out, int out_size, void* d_ws,
                              size_t ws_size, hipStream_t stream) {
  const float* v = (const float*)d_in[0];
  const float* k = (const float*)d_in[1];
  const float* q = (const float*)d_in[2];
  const int* dst = (const int*)d_in[3];
  float* out = (float*)d_out;

  const int E = in_sizes[3];              // 800000
  const int N = in_sizes[2] / (HH * 16);  // 50000

  // Workspace: cursor[N] | eid[N*256] | lgE[E*8]
  char* ws = (char*)d_ws;
  size_t off = 0;
  auto take = [&](size_t bytes) {
    void* p = ws + off;
    off += (bytes + 255) & ~(size_t)255;
    return p;
  };
  int* cursor = (int*)take((size_t)N * sizeof(int));
  int* eid = (int*)take((size_t)N * BSTRIDE * sizeof(int));
  float* lgE = (float*)take((size_t)E * HH * sizeof(float));

  hipMemsetAsync(cursor, 0, (size_t)N * sizeof(int), stream);
  edge_logits_kernel<<<(E * 8 + 255) / 256, 256, 0, stream>>>(k, q, dst, cursor,
                                                              eid, lgE, E);
  node_kernel<<<(N + 3) / 4, 256, 0, stream>>>(v, lgE, cursor, eid, out, N);
}